// Round 1
// baseline (84.103 us; speedup 1.0000x reference)
//
#include <hip/hip_runtime.h>

// FeedForwardQuantum: out = relu(cos(x+theta) @ W1 + b1) @ W2 + b2
// x: [B,S,E=8] fp32, W1: [8,32], W2: [32,8]. 524288 tokens of 8 floats.
// One thread processes TOK_PER_THREAD tokens; weights staged in LDS
// (W1 transposed + W2 row interleaved -> 4 broadcast ds_read_b128 per f).

#define TPB 256
#define TOKT 4   // tokens per thread

__global__ __launch_bounds__(TPB) void ffq_kernel(
    const float4* __restrict__ xv,      // x as float4 pairs: token g -> xv[2g], xv[2g+1]
    const float*  __restrict__ theta,   // [8]
    const float*  __restrict__ w1,      // [8][32] row-major
    const float*  __restrict__ b1,      // [32]
    const float*  __restrict__ w2,      // [32][8] row-major
    const float*  __restrict__ b2,      // [8]
    float4*       __restrict__ outv,    // out as float4 pairs
    int ntok)
{
    // wc[f][0..7]  = W1[0..7][f]  (W1 column f, i.e. W1^T row f)
    // wc[f][8..15] = W2[f][0..7]  (W2 row f)
    __shared__ float wc[32 * 16];
    __shared__ float sb1[32];
    __shared__ float sth[8];
    __shared__ float sb2[8];

    const int tid = threadIdx.x;
    {
        // w1 has 256 elements, tid = e*32 + f
        int e = tid >> 5, f = tid & 31;
        wc[f * 16 + e] = w1[tid];
        // w2 has 256 elements, tid = f*8 + e
        int f2 = tid >> 3, e2 = tid & 7;
        wc[f2 * 16 + 8 + e2] = w2[tid];
    }
    if (tid < 32) sb1[tid] = b1[tid];
    if (tid < 8)  { sth[tid] = theta[tid]; sb2[tid] = b2[tid]; }
    __syncthreads();

    // theta and b2 to registers (broadcast LDS reads, once)
    float th[8], bb2[8];
#pragma unroll
    for (int e = 0; e < 8; ++e) { th[e] = sth[e]; bb2[e] = sb2[e]; }

    const long base   = (long)blockIdx.x * TPB + tid;
    const long stride = (long)gridDim.x * TPB;

    float q[TOKT][8];
    float o[TOKT][8];

#pragma unroll
    for (int t = 0; t < TOKT; ++t) {
        long g = base + (long)t * stride;
        if (g < ntok) {
            float4 a = xv[2 * g];
            float4 c = xv[2 * g + 1];
            q[t][0] = __cosf(a.x + th[0]);
            q[t][1] = __cosf(a.y + th[1]);
            q[t][2] = __cosf(a.z + th[2]);
            q[t][3] = __cosf(a.w + th[3]);
            q[t][4] = __cosf(c.x + th[4]);
            q[t][5] = __cosf(c.y + th[5]);
            q[t][6] = __cosf(c.z + th[6]);
            q[t][7] = __cosf(c.w + th[7]);
        } else {
#pragma unroll
            for (int e = 0; e < 8; ++e) q[t][e] = 0.0f;
        }
#pragma unroll
        for (int e = 0; e < 8; ++e) o[t][e] = bb2[e];
    }

#pragma unroll 4
    for (int f = 0; f < 32; ++f) {
        const float4* wr = (const float4*)(&wc[f * 16]);
        const float4 wa  = wr[0];   // W1^T[f][0..3]
        const float4 wb  = wr[1];   // W1^T[f][4..7]
        const float4 va  = wr[2];   // W2[f][0..3]
        const float4 vb  = wr[3];   // W2[f][4..7]
        const float  bb  = sb1[f];
#pragma unroll
        for (int t = 0; t < TOKT; ++t) {
            float h = bb;
            h = fmaf(q[t][0], wa.x, h);
            h = fmaf(q[t][1], wa.y, h);
            h = fmaf(q[t][2], wa.z, h);
            h = fmaf(q[t][3], wa.w, h);
            h = fmaf(q[t][4], wb.x, h);
            h = fmaf(q[t][5], wb.y, h);
            h = fmaf(q[t][6], wb.z, h);
            h = fmaf(q[t][7], wb.w, h);
            h = fmaxf(h, 0.0f);
            o[t][0] = fmaf(h, va.x, o[t][0]);
            o[t][1] = fmaf(h, va.y, o[t][1]);
            o[t][2] = fmaf(h, va.z, o[t][2]);
            o[t][3] = fmaf(h, va.w, o[t][3]);
            o[t][4] = fmaf(h, vb.x, o[t][4]);
            o[t][5] = fmaf(h, vb.y, o[t][5]);
            o[t][6] = fmaf(h, vb.z, o[t][6]);
            o[t][7] = fmaf(h, vb.w, o[t][7]);
        }
    }

#pragma unroll
    for (int t = 0; t < TOKT; ++t) {
        long g = base + (long)t * stride;
        if (g < ntok) {
            outv[2 * g]     = make_float4(o[t][0], o[t][1], o[t][2], o[t][3]);
            outv[2 * g + 1] = make_float4(o[t][4], o[t][5], o[t][6], o[t][7]);
        }
    }
}

extern "C" void kernel_launch(void* const* d_in, const int* in_sizes, int n_in,
                              void* d_out, int out_size, void* d_ws, size_t ws_size,
                              hipStream_t stream) {
    const float* x     = (const float*)d_in[0];
    const float* theta = (const float*)d_in[1];
    const float* w1    = (const float*)d_in[2];
    const float* b1    = (const float*)d_in[3];
    const float* w2    = (const float*)d_in[4];
    const float* b2    = (const float*)d_in[5];
    float* out = (float*)d_out;

    const int ntok = in_sizes[0] / 8;  // B*S tokens
    const int total_threads = (ntok + TOKT - 1) / TOKT;
    const int grid = (total_threads + TPB - 1) / TPB;

    ffq_kernel<<<grid, TPB, 0, stream>>>(
        (const float4*)x, theta, w1, b1, w2, b2, (float4*)out, ntok);
}